// Round 13
// baseline (336.592 us; speedup 1.0000x reference)
//
#include <hip/hip_runtime.h>

// SemNN — twin-tower masked-pool encoder + classifier.
// B=4096, S=128, D=512, VOCAB=50000, NUM_LABELS=3.
// Confirmed: float inputs bf16 (detector keeps f32 fallback), ids int32,
// masks int-like, OUTPUT f32. ws usage: 16 MB.
//
// Round 21:
//  * r20 post-mortem: ballot+phasing left pool at 139us (VALUBusy 38%,
//    HBM 44%, occ 85%, nothing saturated) => per-REQUEST cost floor:
//    4.2M x 128B random requests, ~8 wave-instr + 1 VMEM roundtrip each.
//  * POOL v4: request width 2B->4B per lane (uint = 2 bf16 cols), 128-col
//    slices, 32768 blocks. Halves request count (2.1M x 256B) and per-byte
//    issue overhead; keeps 4-slice XCD affinity + ballot compaction +
//    vocab phasing. The untested point between r16 (16B/lane, 160us) and
//    r18/r20 (2B/lane, 139us).
//  * Falsifier: pool >=135us => request width immaterial => pattern floor
//    reached; declare ROOFLINE next round.
//  * GEMMs byte-identical to r17/r18/r20 (BK=64, 8 waves, dbuf LDS; g3
//    carries fused logits; d_out zeroing folded into pool slice-3 blocks).

typedef unsigned short u16;
typedef unsigned int u32;
typedef __attribute__((ext_vector_type(8))) short short8;
typedef __attribute__((ext_vector_type(4))) float f32x4;

__device__ __forceinline__ float bfu2f(u16 u) {
    union { unsigned int i; float f; } v;
    v.i = ((unsigned int)u) << 16;
    return v.f;
}

__device__ __forceinline__ u16 f2bfu(float f) {
    union { float f; unsigned int i; } v;
    v.f = f;
    unsigned int x = v.i;
    x += 0x7fffu + ((x >> 16) & 1u);   // RNE
    return (u16)(x >> 16);
}

// tanh(x) = (e^{2x}-1)/(e^{2x}+1) using hw exp2; |x| clamped so e stays
// finite. ~1e-7 rel error, plenty for bf16-rounded outputs.
__device__ __forceinline__ float fast_tanh(float x) {
    float xc = fminf(fmaxf(x, -15.f), 15.f);
    float e = __builtin_amdgcn_exp2f(xc * 2.885390082f);  // 2*log2(e)*x
    return (e - 1.f) / (e + 1.f);
}

// Wave-collective dtype detection; every lane returns flags:
//   bit0: float tensors are bf16 (vs f32); bits2-3: mask type
//   0=int32, 1=byte-bool, 2=bf16, 3=f32
__device__ __forceinline__ int detect_wave(const u16* __restrict__ W,
                                           const unsigned int* __restrict__ m,
                                           int lane)
{
    int cnt = 0;
    int w01 = 1, b01 = 1, lo16 = 0;
    #pragma unroll
    for (int j = lane; j < 256; j += 64) {
        u16 u = W[1024 + 2 * j];
        int e = (u >> 7) & 0xFF;
        cnt += (e >= 0x6A && e <= 0x7E) ? 1 : 0;
        unsigned int v = m[j];
        w01 &= (v <= 1u) ? 1 : 0;
        b01 &= ((v & ~0x01010101u) == 0u) ? 1 : 0;
        lo16 |= ((v & 0xFFFFu) == 0x3F80u) ? 1 : 0;
    }
    #pragma unroll
    for (int off = 32; off > 0; off >>= 1) {
        cnt  += __shfl_down(cnt, off);
        w01  &= __shfl_down(w01, off);
        b01  &= __shfl_down(b01, off);
        lo16 |= __shfl_down(lo16, off);
    }
    int mtype;
    if (w01)        mtype = 0;
    else if (b01)   mtype = 1;
    else if (lo16)  mtype = 2;
    else            mtype = 3;
    int fl = ((cnt >= 128) ? 1 : 0) | (mtype << 2);
    return __shfl(fl, 0);
}

__device__ __forceinline__ int mask_nonzero(const void* __restrict__ msk,
                                            int idx, int mtype)
{
    switch (mtype) {
        case 0:  return ((const int*)msk)[idx] != 0;
        case 1:  return ((const unsigned char*)msk)[idx] != 0;
        case 2:  return ((const u16*)msk)[idx] != 0;
        default: return ((const unsigned int*)msk)[idx] != 0u;
    }
}

// ---------------------------------------------------------------------------
// Kernel 1: column-sliced embedding gather + masked sum-pool -> P [8192,512].
// 32768 blocks x 64 threads (1 wave). bid: row = bid>>2, slice = bid&3
// (128 u16 cols each); bid%... -> XCD affinity per slice. Lane owns one
// u32 (2 bf16 cols); per token one 256B wave request (was 128B in r20).
// Ballot compaction (no atomics); low-vocab-first phasing.
// ---------------------------------------------------------------------------
__global__ __launch_bounds__(64) void pool_kernel(
    const int* __restrict__ ids_a, const int* __restrict__ ids_b,
    const void* __restrict__ mska, const void* __restrict__ mskb,
    const void* __restrict__ W, u16* __restrict__ P,
    float* __restrict__ outz,
    const unsigned int* __restrict__ Mdet)
{
    __shared__ int s_ids[128];
    const int t     = threadIdx.x;         // 0..63
    const int bid   = blockIdx.x;          // 0..32767
    const int slice = bid & 3;             // 4 slices x 128 u16 cols
    const int row   = bid >> 2;            // 0..8191
    const int r     = row & 4095;

    // fold d_out zeroing into this dispatch: slice-3 blocks of rows 0..95
    if (slice == 3 && row < 96) {
        outz[row * 128 + t]      = 0.f;
        outz[row * 128 + 64 + t] = 0.f;
    }

    const int fl = detect_wave((const u16*)W, Mdet, t);
    const bool isbf  = (fl & 1) != 0;
    const int  mtype = (fl >> 2) & 3;

    const int* __restrict__ ids = (row < 4096) ? ids_a : ids_b;
    const void* __restrict__ msk = (row < 4096) ? mska : mskb;

    // ballot compaction, low-vocab (<25600) first then high-vocab
    const int id0 = ids[r * 128 + t];
    const int id1 = ids[r * 128 + 64 + t];
    const int mk0 = mask_nonzero(msk, r * 128 + t, mtype);
    const int mk1 = mask_nonzero(msk, r * 128 + 64 + t, mtype);
    const unsigned long long below = (1ull << t) - 1ull;
    const unsigned long long bl0 = __ballot(mk0 && id0 <  25600);
    const unsigned long long bl1 = __ballot(mk1 && id1 <  25600);
    const unsigned long long bh0 = __ballot(mk0 && id0 >= 25600);
    const unsigned long long bh1 = __ballot(mk1 && id1 >= 25600);
    const int cl0  = __popcll(bl0);
    const int nlow = cl0 + __popcll(bl1);
    const int ch0  = __popcll(bh0);
    const int cnt  = nlow + ch0 + __popcll(bh1);
    if (mk0) {
        const int pos = (id0 < 25600)
                      ? __popcll(bl0 & below)
                      : nlow + __popcll(bh0 & below);
        s_ids[pos] = id0;
    }
    if (mk1) {
        const int pos = (id1 < 25600)
                      ? cl0 + __popcll(bl1 & below)
                      : nlow + ch0 + __popcll(bh1 & below);
        s_ids[pos] = id1;
    }
    __syncthreads();                       // 1 wave: just orders LDS w->r

    float acc0 = 0.f, acc1 = 0.f;          // 2 columns per lane
    if (isbf) {
        // lane owns u32 col index slice*64+t of the 256-u32 row
        const u32* __restrict__ Wb = (const u32*)W + slice * 64 + t;
        int j = 0;
        for (; j + 7 < cnt; j += 8) {      // 8 x 256B requests in flight
            const u32 v0 = Wb[(size_t)s_ids[j + 0] * 256];
            const u32 v1 = Wb[(size_t)s_ids[j + 1] * 256];
            const u32 v2 = Wb[(size_t)s_ids[j + 2] * 256];
            const u32 v3 = Wb[(size_t)s_ids[j + 3] * 256];
            const u32 v4 = Wb[(size_t)s_ids[j + 4] * 256];
            const u32 v5 = Wb[(size_t)s_ids[j + 5] * 256];
            const u32 v6 = Wb[(size_t)s_ids[j + 6] * 256];
            const u32 v7 = Wb[(size_t)s_ids[j + 7] * 256];
            acc0 += ((bfu2f((u16)v0) + bfu2f((u16)v1)) +
                     (bfu2f((u16)v2) + bfu2f((u16)v3))) +
                    ((bfu2f((u16)v4) + bfu2f((u16)v5)) +
                     (bfu2f((u16)v6) + bfu2f((u16)v7)));
            acc1 += ((bfu2f((u16)(v0 >> 16)) + bfu2f((u16)(v1 >> 16))) +
                     (bfu2f((u16)(v2 >> 16)) + bfu2f((u16)(v3 >> 16)))) +
                    ((bfu2f((u16)(v4 >> 16)) + bfu2f((u16)(v5 >> 16))) +
                     (bfu2f((u16)(v6 >> 16)) + bfu2f((u16)(v7 >> 16))));
        }
        for (; j < cnt; ++j) {
            const u32 v = Wb[(size_t)s_ids[j] * 256];
            acc0 += bfu2f((u16)v);
            acc1 += bfu2f((u16)(v >> 16));
        }
    } else {
        const float* __restrict__ Wf = (const float*)W + slice * 128 + 2 * t;
        int j = 0;
        for (; j + 3 < cnt; j += 4) {
            const float2 a = *(const float2*)(Wf + (size_t)s_ids[j + 0] * 512);
            const float2 b = *(const float2*)(Wf + (size_t)s_ids[j + 1] * 512);
            const float2 c = *(const float2*)(Wf + (size_t)s_ids[j + 2] * 512);
            const float2 d = *(const float2*)(Wf + (size_t)s_ids[j + 3] * 512);
            acc0 += (a.x + b.x) + (c.x + d.x);
            acc1 += (a.y + b.y) + (c.y + d.y);
        }
        for (; j < cnt; ++j) {
            const float2 a = *(const float2*)(Wf + (size_t)s_ids[j] * 512);
            acc0 += a.x;
            acc1 += a.y;
        }
    }
    const u32 out = (u32)f2bfu(acc0) | ((u32)f2bfu(acc1) << 16);
    ((u32*)P)[(size_t)row * 256 + slice * 64 + t] = out;
}

// ---------------------------------------------------------------------------
// GEMM tile, BK=64 (r17, measured best): C[m0:+128, n0:+64] over K (N=512).
// 512 thr, 8 waves 4m x 2n (wave 32x32, acc 2x2). A LDS [128][72] u16;
// B LDS [64][72] 8-chunk rotate swizzle. Double-buffered, 1 barrier/step.
// ---------------------------------------------------------------------------
#define GEMM_KLOOP_BK64                                                        \
    FETCH(0)                                                                   \
    STORE(0)                                                                   \
    FETCH(64)                                                                  \
    __syncthreads();                                                           \
    int p = 0;                                                                 \
    for (int k0 = 0; k0 < K; k0 += 64) {                                       \
        if (k0 + 64 < K) {                                                     \
            STORE(p ^ 1)                                                       \
            if (k0 + 128 < K) FETCH(k0 + 128)                                  \
        }                                                                      \
        const u16* Ap  = As0 + p * 9216;                                       \
        const u16* Bp2 = Bs0 + p * 4608;                                       \
        short8 af0[2], af1[2], bf0[2], bf1[2];                                 \
        _Pragma("unroll")                                                      \
        for (int i = 0; i < 2; ++i) {                                          \
            af0[i] = *(const short8*)&Ap[(wm + i * 16 + lm) * 72 + kq * 8];    \
            af1[i] = *(const short8*)&Ap[(wm + i * 16 + lm) * 72 + 32 + kq * 8];\
        }                                                                      \
        _Pragma("unroll")                                                      \
        for (int j = 0; j < 2; ++j) {                                          \
            const int n = wn + j * 16 + lm;                                    \
            bf0[j] = *(const short8*)&Bp2[n * 72 + ((kq + (n >> 3)) & 7) * 8]; \
            bf1[j] = *(const short8*)&Bp2[n * 72 + ((4 + kq + (n >> 3)) & 7) * 8];\
        }                                                                      \
        _Pragma("unroll")                                                      \
        for (int i = 0; i < 2; ++i)                                            \
            _Pragma("unroll")                                                  \
            for (int j = 0; j < 2; ++j) {                                      \
                acc[i][j] = __builtin_amdgcn_mfma_f32_16x16x32_bf16(           \
                    af0[i], bf0[j], acc[i][j], 0, 0, 0);                       \
                acc[i][j] = __builtin_amdgcn_mfma_f32_16x16x32_bf16(           \
                    af1[i], bf1[j], acc[i][j], 0, 0, 0);                       \
            }                                                                  \
        if (k0 + 64 < K) __syncthreads();                                      \
        p ^= 1;                                                                \
    }

#define GEMM_FETCH_STORE_BK64                                                  \
    uint4 ra0, ra1, rbb;                                                       \
    float4 rf0, rf1;                                                           \
    (void)rf0; (void)rf1;

#define FETCH(k0)                                                             \
    {                                                                         \
        const int kg = (k0) + ac;                                             \
        const u16* base = (kg < K1) ? (A + kg) : (A2 + (kg - K1));            \
        ra0 = *(const uint4*)(base + (size_t)(m0 + ar) * 512);                \
        ra1 = *(const uint4*)(base + (size_t)(m0 + ar + 64) * 512);           \
        if constexpr (ISBF) {                                                 \
            rbb = *(const uint4*)(Bb + (size_t)((k0) + bkr) * 512 + n0 + nb); \
        } else {                                                              \
            const float* Bp_ = Bf + (size_t)((k0) + bkr) * 512 + n0 + nb;     \
            rf0 = *(const float4*)(Bp_ + 0);                                  \
            rf1 = *(const float4*)(Bp_ + 4);                                  \
        }                                                                     \
    }

#define STORE(pp)                                                             \
    {                                                                         \
        *(uint4*)&As0[(pp) * 9216 + ar * 72 + ac] = ra0;                      \
        *(uint4*)&As0[(pp) * 9216 + (ar + 64) * 72 + ac] = ra1;               \
        u16 bvals[8];                                                         \
        if constexpr (ISBF) {                                                 \
            union { uint4 v; u16 s[8]; } ub; ub.v = rbb;                      \
            _Pragma("unroll")                                                 \
            for (int i = 0; i < 8; ++i) bvals[i] = ub.s[i];                   \
        } else {                                                              \
            bvals[0] = f2bfu(rf0.x); bvals[1] = f2bfu(rf0.y);                 \
            bvals[2] = f2bfu(rf0.z); bvals[3] = f2bfu(rf0.w);                 \
            bvals[4] = f2bfu(rf1.x); bvals[5] = f2bfu(rf1.y);                 \
            bvals[6] = f2bfu(rf1.z); bvals[7] = f2bfu(rf1.w);                 \
        }                                                                     \
        const int slot_ = (((bkr >> 3) + jn) & 7) * 8 + (bkr & 7);            \
        _Pragma("unroll")                                                     \
        for (int i = 0; i < 8; ++i)                                           \
            Bs0[(pp) * 4608 + (nb + i) * 72 + slot_] = bvals[i];              \
    }

template<bool ISBF>
__device__ __forceinline__ void gemm_tile(
    const u16* __restrict__ A, const u16* __restrict__ A2, const int K1,
    const void* __restrict__ Bv, const void* __restrict__ biasv,
    u16* __restrict__ C, const int K, const int m0, const int n0,
    u16* __restrict__ As0, u16* __restrict__ Bs0)
{
    const int tid  = threadIdx.x;          // 0..511
    const int lane = tid & 63;
    const int wid = tid >> 6;              // 0..7
    const int wm  = (wid & 3) * 32;
    const int wn  = (wid >> 2) * 32;
    const int ar  = tid >> 3;              // 0..63 (A rows; also +64)
    const int ac  = (tid & 7) * 8;         // k-col within BK=64
    const int bkr = tid >> 3;              // 0..63 B k-row
    const int jn  = tid & 7;
    const int nb  = jn * 8;
    const int lm = lane & 15;
    const int kq = lane >> 4;

    const u16*   Bb = (const u16*)Bv;
    const float* Bf = (const float*)Bv;

    f32x4 acc[2][2];
    #pragma unroll
    for (int i = 0; i < 2; ++i)
        #pragma unroll
        for (int j = 0; j < 2; ++j)
            acc[i][j] = (f32x4){0.f, 0.f, 0.f, 0.f};

    GEMM_FETCH_STORE_BK64
    GEMM_KLOOP_BK64

    // epilogue: bias + tanh + bf16 store
    #pragma unroll
    for (int j = 0; j < 2; ++j) {
        const int n = n0 + wn + j * 16 + lm;
        const float bsv = ISBF ? bfu2f(((const u16*)biasv)[n])
                               : ((const float*)biasv)[n];
        #pragma unroll
        for (int i = 0; i < 2; ++i) {
            #pragma unroll
            for (int r = 0; r < 4; ++r) {
                const int m = m0 + wm + i * 16 + kq * 4 + r;
                C[(size_t)m * 512 + n] = f2bfu(fast_tanh(acc[i][j][r] + bsv));
            }
        }
    }
}

__global__ __launch_bounds__(512, 4) void gemm_mfma(
    const u16* __restrict__ A, const u16* __restrict__ A2, int K1,
    const void* __restrict__ B, const void* __restrict__ bias,
    u16* __restrict__ C, int K,
    const u16* __restrict__ Wdet, const unsigned int* __restrict__ Mdet)
{
    __shared__ __align__(16) u16 As[2 * 128 * 72];   // 36.9 KB
    __shared__ __align__(16) u16 Bs[2 * 64 * 72];    // 18.4 KB
    __shared__ int s_flags;

    if (threadIdx.x < 64) {
        int fl = detect_wave(Wdet, Mdet, threadIdx.x);
        if (threadIdx.x == 0) s_flags = fl;
    }
    __syncthreads();
    const int m0 = blockIdx.x * 128;
    const int n0 = blockIdx.y * 64;
    if (s_flags & 1) gemm_tile<true >(A, A2, K1, B, bias, C, K, m0, n0, As, Bs);
    else             gemm_tile<false>(A, A2, K1, B, bias, C, K, m0, n0, As, Bs);
}

// ---------------------------------------------------------------------------
// Kernel 3: GEMM3 + logits (r17). H kept in regs; logits via shfl-reduce
// over lm lanes + f32 atomicAdd into zeroed d_out.
// ---------------------------------------------------------------------------
template<bool ISBF>
__device__ __forceinline__ void g3_body(
    const u16* __restrict__ A, const u16* __restrict__ A2, const int K1,
    const void* __restrict__ Bv, const void* __restrict__ biasv,
    const void* __restrict__ w2v, const void* __restrict__ cb2v,
    float* __restrict__ outp, const int K,
    u16* __restrict__ As0, u16* __restrict__ Bs0)
{
    const int tid  = threadIdx.x;
    const int lane = tid & 63;
    const int wid = tid >> 6;
    const int wm  = (wid & 3) * 32;
    const int wn  = (wid >> 2) * 32;
    const int ar  = tid >> 3;
    const int ac  = (tid & 7) * 8;
    const int bkr = tid >> 3;
    const int jn  = tid & 7;
    const int nb  = jn * 8;
    const int lm = lane & 15;
    const int kq = lane >> 4;
    const int m0 = (blockIdx.x & 31) * 128;
    const int n0 = (blockIdx.x >> 5) * 64;

    const u16*   Bb = (const u16*)Bv;
    const float* Bf = (const float*)Bv;

    f32x4 acc[2][2];
    #pragma unroll
    for (int i = 0; i < 2; ++i)
        #pragma unroll
        for (int j = 0; j < 2; ++j)
            acc[i][j] = (f32x4){0.f, 0.f, 0.f, 0.f};

    GEMM_FETCH_STORE_BK64
    GEMM_KLOOP_BK64

    // epilogue: H = tanh(acc + cb1[n]); logits partials; lm-reduce; atomics
    float lg[2][4][3];
    #pragma unroll
    for (int i = 0; i < 2; ++i)
        #pragma unroll
        for (int r = 0; r < 4; ++r)
            #pragma unroll
            for (int l = 0; l < 3; ++l) lg[i][r][l] = 0.f;

    #pragma unroll
    for (int j = 0; j < 2; ++j) {
        const int n = n0 + wn + j * 16 + lm;
        const float bsv = ISBF ? bfu2f(((const u16*)biasv)[n])
                               : ((const float*)biasv)[n];
        float wc[3];
        #pragma unroll
        for (int l = 0; l < 3; ++l)
            wc[l] = ISBF ? bfu2f(((const u16*)w2v)[n * 3 + l])
                         : ((const float*)w2v)[n * 3 + l];
        #pragma unroll
        for (int i = 0; i < 2; ++i)
            #pragma unroll
            for (int r = 0; r < 4; ++r) {
                const float h = fast_tanh(acc[i][j][r] + bsv);
                #pragma unroll
                for (int l = 0; l < 3; ++l) lg[i][r][l] += h * wc[l];
            }
    }
    #pragma unroll
    for (int off = 1; off <= 8; off <<= 1)
        #pragma unroll
        for (int i = 0; i < 2; ++i)
            #pragma unroll
            for (int r = 0; r < 4; ++r)
                #pragma unroll
                for (int l = 0; l < 3; ++l)
                    lg[i][r][l] += __shfl_xor(lg[i][r][l], off);

    if (lm == 0) {
        const bool addb = (n0 == 0) && (wn == 0);   // exactly one per (m,l)
        float cb[3];
        #pragma unroll
        for (int l = 0; l < 3; ++l)
            cb[l] = ISBF ? bfu2f(((const u16*)cb2v)[l])
                         : ((const float*)cb2v)[l];
        #pragma unroll
        for (int i = 0; i < 2; ++i)
            #pragma unroll
            for (int r = 0; r < 4; ++r) {
                const int m = m0 + wm + i * 16 + kq * 4 + r;
                #pragma unroll
                for (int l = 0; l < 3; ++l) {
                    float v = lg[i][r][l];
                    if (addb) v += cb[l];
                    atomicAdd(&outp[m * 3 + l], v);
                }
            }
    }
}

__global__ __launch_bounds__(512, 4) void gemm3_logits(
    const u16* __restrict__ A, const u16* __restrict__ A2, int K1,
    const void* __restrict__ B, const void* __restrict__ bias,
    const void* __restrict__ w2, const void* __restrict__ cb2,
    float* __restrict__ out, int K,
    const u16* __restrict__ Wdet, const unsigned int* __restrict__ Mdet)
{
    __shared__ __align__(16) u16 As[2 * 128 * 72];
    __shared__ __align__(16) u16 Bs[2 * 64 * 72];
    __shared__ int s_flags;

    if (threadIdx.x < 64) {
        int fl = detect_wave(Wdet, Mdet, threadIdx.x);
        if (threadIdx.x == 0) s_flags = fl;
    }
    __syncthreads();
    if (s_flags & 1)
        g3_body<true >(A, A2, K1, B, bias, w2, cb2, out, K, As, Bs);
    else
        g3_body<false>(A, A2, K1, B, bias, w2, cb2, out, K, As, Bs);
}

// ---------------------------------------------------------------------------
extern "C" void kernel_launch(void* const* d_in, const int* in_sizes, int n_in,
                              void* d_out, int out_size, void* d_ws, size_t ws_size,
                              hipStream_t stream)
{
    const int* ids_a  = (const int*)d_in[0];
    const int* ids_b  = (const int*)d_in[1];
    const void* mask_a = d_in[2];
    const void* mask_b = d_in[3];
    const void* W_emb  = d_in[4];
    const void* enc_w1 = d_in[5];
    const void* enc_b1 = d_in[6];
    const void* enc_w2 = d_in[7];
    const void* enc_b2 = d_in[8];
    const void* cls_w1 = d_in[9];
    const void* cls_b1 = d_in[10];
    const void* cls_w2 = d_in[11];
    const void* cls_b2 = d_in[12];

    const u16* Wdet = (const u16*)W_emb;
    const unsigned int* Mdet = (const unsigned int*)mask_a;

    u16* buf0 = (u16*)d_ws;                          // 8192*512 bf16 = 8 MB
    u16* buf1 = buf0 + (size_t)8192 * 512;           // 8 MB
    float* outp = (float*)d_out;

    // P -> buf0 (rows 0..4095 side a, 4096..8191 side b); also zeroes d_out.
    // 32768 blocks: row = bid>>2, col-slice = bid&3 (128 u16 cols each)
    pool_kernel<<<32768, 64, 0, stream>>>(ids_a, ids_b, mask_a, mask_b,
                                          W_emb, buf0, outp, Mdet);

    // X1 = tanh(P @ w1 + b1) -> buf1
    gemm_mfma<<<dim3(64, 8), 512, 0, stream>>>(
        buf0, buf0, 512, enc_w1, enc_b1, buf1, 512, Wdet, Mdet);

    // X2 = tanh(X1 @ w2 + b2) -> buf0
    gemm_mfma<<<dim3(64, 8), 512, 0, stream>>>(
        buf1, buf1, 512, enc_w2, enc_b2, buf0, 512, Wdet, Mdet);

    // logits = tanh([va|vb]@cw1+cb1) @ cw2 + cb2 -> d_out (f32, atomics)
    gemm3_logits<<<256, 512, 0, stream>>>(
        buf0, buf0 + (size_t)4096 * 512, 512, cls_w1, cls_b1,
        cls_w2, cls_b2, outp, 1024, Wdet, Mdet);
}